// Round 3
// baseline (174.738 us; speedup 1.0000x reference)
//
#include <hip/hip_runtime.h>
#include <hip/hip_bf16.h>
#include <hip/hip_cooperative_groups.h>

namespace cg = cooperative_groups;

#define B_   4
#define LQ_  128
#define LF_  64
#define NW_  2
#define NFR_ 8
#define E_   128
#define D_   128
#define V_   64
#define NWF_ (NW_*NFR_)            // 16

using bf16 = __hip_bfloat16;
typedef unsigned short u16;
typedef unsigned int   u32;
typedef __attribute__((ext_vector_type(8))) short  bf16x8;
typedef __attribute__((ext_vector_type(2))) float  f32x2;
typedef __attribute__((ext_vector_type(4))) float  f32x4;
typedef __attribute__((ext_vector_type(4))) u32    u32x4;

// ---- ws layout (float-index units) ----
#define WS_PWT   0        // [128][128] u16 projW^T   8192 f
#define WS_QAT   8192     // [64][128] u16 qattW^T    4096 f
#define WS_W3T   12288    // [64][128] u16 qfW^T      4096 f
#define WS_WFT   16384    // [64][128] u16 fattW^T    4096 f
#define WS_E2    20480    // [64][128] f32            8192 f
#define WS_QPB   28672    // [4][128][128] u16       32768 f

// ---- out layout (element units; u16 if BF out else f32) ----
#define OUT_FRAGCODE  0       // (B,NW,NFR,D)   8192
#define OUT_QUERYCODE 8192    // (B,NW,NFR,D)   8192
#define OUT_SELFATT   16384   // (B,NW,NFR,LF)  4096
#define OUT_QFGATE    20480   // (B,16,LQ)      8192
#define OUT_QUERY     28672   // (B,LQ,D)       65536

// ---- k_all LDS layout (bytes) ----
#define L_FP   0        // u16 [64][128] swizzled    16384
#define L_QP   16384    // u16 [32][128] swizzled     8192
#define L_FA   24576    // u16 [64][72] f_att         9216
#define L_QAT  33792    // u16 [32][72]               4608
#define L_SAW  38400    // f32 [128]                   512
#define L_ATT  38912    // f32 [64]                    256
#define L_RED  39168    // f32 [512]                  2048
#define L_PM   41216    // u16 [4][32][64] pmax      16384
#define L_TOT  57600
// qcode overlay (after 2nd grid sync; reuses smem from offset 0)
#define LQ_SQ    0        // u16 [128][128]           32768
#define LQ_SN    32768    // f32 [128]                  512
#define LQ_SP    33280    // f32 [2]                      8
#define LQ_SR    33536    // f32 [4][128]              2048

__device__ __forceinline__ float us2f(u16 v) { return __uint_as_float((u32)v << 16); }
__device__ __forceinline__ float lo2f(u32 v) { return __uint_as_float(v << 16); }
__device__ __forceinline__ float hi2f(u32 v) { return __uint_as_float(v & 0xffff0000u); }
__device__ __forceinline__ u16 f2b_raw(float f) {
    u32 u = __float_as_uint(f);
    return (u16)((u + 0x7fffu + ((u >> 16) & 1u)) >> 16);
}
__device__ __forceinline__ u32 pk2(float hi, float lo) {
    return __builtin_amdgcn_perm(__float_as_uint(hi), __float_as_uint(lo), 0x07060302u);
}
template<bool BF> __device__ __forceinline__ float LD(const void* p, int i) {
    return BF ? us2f(((const u16*)p)[i]) : ((const float*)p)[i];
}
template<bool BF> __device__ __forceinline__ void ST(void* p, int i, float v) {
    if (BF) ((u16*)p)[i] = f2b_raw(v); else ((float*)p)[i] = v;
}
template<bool BF> __device__ __forceinline__ u16 LDB(const void* p, int i) {
    return BF ? ((const u16*)p)[i] : f2b_raw(((const float*)p)[i]);
}
__device__ __forceinline__ bool is_bf(const void* qmask) {
    return ((const u16*)qmask)[0] == 0x3F80u;
}
// A-fragment (16 rows x 32 k) direct from global row-major [*,128]
template<bool BF>
__device__ __forceinline__ bf16x8 loadA(const void* x, int row, int kt, int quad) {
    int off = row * 128 + kt * 32 + quad * 8;
    if (BF) return *(const bf16x8*)((const u16*)x + off);
    f32x4 a = *(const f32x4*)((const float*)x + off);
    f32x4 c = *(const f32x4*)((const float*)x + off + 4);
    u32x4 av;
    av.x = pk2(a.y, a.x); av.y = pk2(a.w, a.z);
    av.z = pk2(c.y, c.x); av.w = pk2(c.w, c.z);
    return __builtin_bit_cast(bf16x8, av);
}

// ============ prep (16 designated blocks): transpose weights to [n][k] =====
template<bool BF>
__device__ __forceinline__ void prep_body(const void* src, u16* dst, u16* stg,
                                          int N, int k0)
{
    int t = threadIdx.x, st = N + 1, total = 32 * N;
    for (int i = t; i < total; i += 512) {
        int k = i / N, v = i % N;   // N is 64 or 128
        stg[k * st + v] = LDB<BF>(src, (k0 + k) * N + v);
    }
    __syncthreads();
    for (int j = t; j < total; j += 512) {
        int n = j >> 5, kk = j & 31;
        dst[n * 128 + k0 + kk] = stg[kk * st + n];
    }
}

// ============ main phase: 256 blocks (qt, bwf) x 512 thr ===================
// XCD-spread decode: qt = bx>>6 (4 groups of 64), bwf = bx&63 -> the heavy
// epilogue blocks (fragatt: qt == bwf&3) and export blocks (bwf&15==0) are
// distributed evenly across the 8 XCDs instead of clustering on XCD 0/4.
template<bool BF>
__device__ __forceinline__ void main_body(
    const void* query, const void* fragment, const void* qmask, const void* fmask,
    const void* projB, const void* saW, const void* gatew, const void* valw,
    float* ws, void* out, char* smem)
{
    u16*   s_fp  = (u16*)(smem + L_FP);
    u16*   s_qp  = (u16*)(smem + L_QP);
    u16*   s_fa  = (u16*)(smem + L_FA);
    u16*   s_qat = (u16*)(smem + L_QAT);
    float* s_saw = (float*)(smem + L_SAW);
    float* s_att = (float*)(smem + L_ATT);
    float* s_red = (float*)(smem + L_RED);
    u16*   s_pm  = (u16*)(smem + L_PM);

    int bx = blockIdx.x;
    int qt = bx >> 6, bwf = bx & 63, b = bwf >> 4;
    int t = threadIdx.x, lane = t & 63, w = t >> 6;
    int m = lane & 15, quad = lane >> 4;
    int sk = (m & 7) << 3;
    const u16* pwt = (const u16*)(ws + WS_PWT);
    const u16* qatw = (const u16*)(ws + WS_QAT);
    const u16* w3t = (const u16*)(ws + WS_W3T);
    const u16* wft = (const u16*)(ws + WS_WFT);
    bool do_fragatt = (qt == (bwf & 3));
    bool do_export  = ((bwf & 15) == 0);

    // ---- Phase A: projections ----
    if (w < 4) {
        // fragment rows [w*16, w*16+16)
        bf16x8 afr[4];
        #pragma unroll
        for (int kt = 0; kt < 4; ++kt)
            afr[kt] = loadA<BF>(fragment, bwf * 64 + w * 16 + m, kt, quad);
        #pragma unroll
        for (int nt = 0; nt < 8; ++nt) {
            int n = nt * 16 + m;
            float bv = LD<BF>(projB, n);
            f32x4 acc = (f32x4){bv, bv, bv, bv};
            #pragma unroll
            for (int kt = 0; kt < 4; ++kt) {
                bf16x8 bw = *(const bf16x8*)(pwt + n * 128 + kt * 32 + quad * 8);
                acc = __builtin_amdgcn_mfma_f32_16x16x32_bf16(afr[kt], bw, acc, 0, 0, 0);
            }
            #pragma unroll
            for (int rr = 0; rr < 4; ++rr) {
                int row = w * 16 + quad * 4 + rr;
                s_fp[row * 128 + (n ^ ((row & 7) << 3))] = f2b_raw(acc[rr]);
            }
        }
    } else if (w < 6) {
        // query rows qt*32 + (w-4)*16 + [0,16)
        int q0 = (w - 4) * 16;
        bf16x8 afq[4];
        #pragma unroll
        for (int kt = 0; kt < 4; ++kt)
            afq[kt] = loadA<BF>(query, b * 128 + qt * 32 + q0 + m, kt, quad);
        #pragma unroll
        for (int nt = 0; nt < 8; ++nt) {
            int n = nt * 16 + m;
            float bv = LD<BF>(projB, n);
            f32x4 acc = (f32x4){bv, bv, bv, bv};
            #pragma unroll
            for (int kt = 0; kt < 4; ++kt) {
                bf16x8 bw = *(const bf16x8*)(pwt + n * 128 + kt * 32 + quad * 8);
                acc = __builtin_amdgcn_mfma_f32_16x16x32_bf16(afq[kt], bw, acc, 0, 0, 0);
            }
            #pragma unroll
            for (int rr = 0; rr < 4; ++rr) {
                int row = q0 + quad * 4 + rr;
                s_qp[row * 128 + (n ^ ((row & 7) << 3))] = f2b_raw(acc[rr]);
            }
        }
    }
    __syncthreads();

    // ---- Phase B: f_att (waves 0-3) and q_att (waves 4-5) ----
    if (w < 4) {
        bf16x8 afa[4];
        #pragma unroll
        for (int kt = 0; kt < 4; ++kt)
            afa[kt] = *(const bf16x8*)&s_fp[(w * 16 + m) * 128 + ((kt * 32 + quad * 8) ^ sk)];
        #pragma unroll
        for (int vt = 0; vt < 4; ++vt) {
            f32x4 a0 = (f32x4){0.f, 0.f, 0.f, 0.f};
            #pragma unroll
            for (int kt = 0; kt < 4; ++kt) {
                bf16x8 wk = *(const bf16x8*)(wft + (vt * 16 + m) * 128 + kt * 32 + quad * 8);
                a0 = __builtin_amdgcn_mfma_f32_16x16x32_bf16(afa[kt], wk, a0, 0, 0, 0);
            }
            #pragma unroll
            for (int r = 0; r < 4; ++r)
                s_fa[(w * 16 + quad * 4 + r) * 72 + vt * 16 + m] = f2b_raw(a0[r]);
        }
    } else if (w < 6) {
        int q0 = (w - 4) * 16;
        bf16x8 aq[4];
        #pragma unroll
        for (int kt = 0; kt < 4; ++kt)
            aq[kt] = *(const bf16x8*)&s_qp[(q0 + m) * 128 + ((kt * 32 + quad * 8) ^ sk)];
        #pragma unroll
        for (int vt = 0; vt < 4; ++vt) {
            f32x4 a0 = (f32x4){0.f, 0.f, 0.f, 0.f};
            #pragma unroll
            for (int kt = 0; kt < 4; ++kt) {
                bf16x8 bk = *(const bf16x8*)(qatw + (vt * 16 + m) * 128 + kt * 32 + quad * 8);
                a0 = __builtin_amdgcn_mfma_f32_16x16x32_bf16(aq[kt], bk, a0, 0, 0, 0);
            }
            #pragma unroll
            for (int r = 0; r < 4; ++r)
                s_qat[(q0 + quad * 4 + r) * 72 + vt * 16 + m] = f2b_raw(a0[r]);
        }
    }
    __syncthreads();

    // ---- Phase C: l-loop. wave = (qsub, lq) -> 16q x 16l x ALL 4 vt ----
    // af (q*f elementwise, packed bf16) built ONCE per (q,l) and amortized
    // over 16 MFMAs.
    int qsub = w & 1, lq = w >> 1;          // lq in [0,4): 16-l quarter
    bf16x8 w3f[4][4];
    #pragma unroll
    for (int vt = 0; vt < 4; ++vt)
        #pragma unroll
        for (int kt = 0; kt < 4; ++kt)
            w3f[vt][kt] = *(const bf16x8*)(w3t + (vt * 16 + m) * 128 + kt * 32 + quad * 8);
    f32x2 qp2[4][4];
    {
        #pragma unroll
        for (int kt = 0; kt < 4; ++kt) {
            bf16x8 aq2 = *(const bf16x8*)&s_qp[(qsub * 16 + m) * 128 + ((kt * 32 + quad * 8) ^ sk)];
            u32x4 uv = __builtin_bit_cast(u32x4, aq2);
            qp2[kt][0] = (f32x2){lo2f(uv.x), hi2f(uv.x)};
            qp2[kt][1] = (f32x2){lo2f(uv.y), hi2f(uv.y)};
            qp2[kt][2] = (f32x2){lo2f(uv.z), hi2f(uv.z)};
            qp2[kt][3] = (f32x2){lo2f(uv.w), hi2f(uv.w)};
        }
    }
    float mx[4][4];
    #pragma unroll
    for (int vt = 0; vt < 4; ++vt)
        #pragma unroll
        for (int r = 0; r < 4; ++r) mx[vt][r] = -1e30f;

    int lbase = lq * 16;
    #pragma unroll 2
    for (int li = 0; li < 16; ++li) {
        int l = lbase + li;
        int sw = (l & 7) << 3;
        bf16x8 af[4];
        #pragma unroll
        for (int kt = 0; kt < 4; ++kt) {
            u32x4 fv = *(const u32x4*)&s_fp[l * 128 + ((kt * 32 + quad * 8) ^ sw)];
            f32x2 p0 = qp2[kt][0] * (f32x2){lo2f(fv.x), hi2f(fv.x)};
            f32x2 p1 = qp2[kt][1] * (f32x2){lo2f(fv.y), hi2f(fv.y)};
            f32x2 p2 = qp2[kt][2] * (f32x2){lo2f(fv.z), hi2f(fv.z)};
            f32x2 p3 = qp2[kt][3] * (f32x2){lo2f(fv.w), hi2f(fv.w)};
            u32x4 av;
            av.x = pk2(p0.y, p0.x);
            av.y = pk2(p1.y, p1.x);
            av.z = pk2(p2.y, p2.x);
            av.w = pk2(p3.y, p3.x);
            af[kt] = __builtin_bit_cast(bf16x8, av);
        }
        #pragma unroll
        for (int vt = 0; vt < 4; ++vt) {
            float fa = us2f(s_fa[l * 72 + vt * 16 + m]);
            f32x4 acc = (f32x4){fa, fa, fa, fa};
            #pragma unroll
            for (int kt = 0; kt < 4; ++kt)
                acc = __builtin_amdgcn_mfma_f32_16x16x32_bf16(af[kt], w3f[vt][kt], acc, 0, 0, 0);
            #pragma unroll
            for (int r = 0; r < 4; ++r) mx[vt][r] = fmaxf(mx[vt][r], acc[r]);
        }
    }
    // partial maxes to dedicated s_pm (bank-swizzled)
    #pragma unroll
    for (int vt = 0; vt < 4; ++vt)
        #pragma unroll
        for (int r = 0; r < 4; ++r) {
            int q = qsub * 16 + quad * 4 + r;
            s_pm[(lq * 32 + q) * 64 + ((vt * 16 + m) ^ (((q >> 2) & 3) << 4))] = f2b_raw(mx[vt][r]);
        }
    __syncthreads();

    // ---- Phase D: gate / e2 epilogue (q = t>>4 in [0,32), vg = t&15) ----
    {
        int q = t >> 4, vg = t & 15;
        int gq = qt * 32 + q;
        int swq = ((q >> 2) & 3) << 4;
        float gp = 0.f, ep = 0.f;
        #pragma unroll
        for (int jj = 0; jj < 4; ++jj) {
            int v = vg * 4 + jj;
            int c = v ^ swq;
            float m01 = fmaxf(us2f(s_pm[q * 64 + c]),        us2f(s_pm[(32 + q) * 64 + c]));
            float m23 = fmaxf(us2f(s_pm[(64 + q) * 64 + c]), us2f(s_pm[(96 + q) * 64 + c]));
            float qf = fmaxf(m01, m23) + us2f(s_qat[q * 72 + v]);
            gp += qf * LD<BF>(gatew, v);
            ep += qf * LD<BF>(valw, v);
        }
        #pragma unroll
        for (int off = 1; off <= 8; off <<= 1) {
            gp += __shfl_xor(gp, off, 64);
            ep += __shfl_xor(ep, off, 64);
        }
        if (vg == 0) {
            float qm = LD<BF>(qmask, b * 128 + gq);
            float g = (1.0f / (1.0f + expf(-gp))) * qm;
            ST<BF>(out, OUT_QFGATE + bwf * LQ_ + gq, g);
            ws[WS_E2 + bwf * 128 + gq] = expf(ep) * qm;
        }
    }

    // ---- qp export (bwf%16==0 blocks; each exports its own 32 q rows) ----
    if (do_export) {
        u16* qpb = (u16*)(ws + WS_QPB);
        #pragma unroll
        for (int it = 0; it < 8; ++it) {
            int i = t + 512 * it;              // 4096 = 32*128
            int row = i >> 7, col = i & 127;
            u16 raw = s_qp[row * 128 + (col ^ ((row & 7) << 3))];
            int gr = b * 128 + qt * 32 + row;
            ST<BF>(out, OUT_QUERY + gr * 128 + col, us2f(raw));
            qpb[gr * 128 + col] = raw;
        }
    }

    // ---- fragment self-attention + frag_code (XCD-spread assignment) ----
    if (do_fragatt) {
        if (t < 128) s_saw[t] = LD<BF>(saW, ((bwf >> 3) & 1) * 128 + t);
        __syncthreads();
        {
            int l = t >> 3, j8 = t & 7;
            int swz = (l & 7) << 3;
            float p = 0.f;
            #pragma unroll
            for (int seg = 0; seg < 2; ++seg) {
                int koff = j8 * 16 + seg * 8;
                u32x4 fv = *(const u32x4*)&s_fp[l * 128 + (koff ^ swz)];
                const float* swp = &s_saw[koff];
                p += lo2f(fv.x) * swp[0] + hi2f(fv.x) * swp[1]
                   + lo2f(fv.y) * swp[2] + hi2f(fv.y) * swp[3]
                   + lo2f(fv.z) * swp[4] + hi2f(fv.z) * swp[5]
                   + lo2f(fv.w) * swp[6] + hi2f(fv.w) * swp[7];
            }
            p += __shfl_xor(p, 1, 64);
            p += __shfl_xor(p, 2, 64);
            p += __shfl_xor(p, 4, 64);
            if (j8 == 0) s_att[l] = expf(p) * LD<BF>(fmask, bwf * LF_ + l);
        }
        __syncthreads();
        if (t < 64) {
            float e = s_att[t], s = e;
            #pragma unroll
            for (int off = 1; off <= 32; off <<= 1) s += __shfl_xor(s, off, 64);
            float nrm = e / (s + 1e-7f);
            s_att[t] = nrm;
            ST<BF>(out, OUT_SELFATT + bwf * LF_ + t, nrm);
        }
        __syncthreads();
        {
            int d = t & 127, grp = t >> 7;
            float fc = 0.f;
            #pragma unroll
            for (int li2 = 0; li2 < 16; ++li2) {
                int l2 = grp * 16 + li2;
                fc += us2f(s_fp[l2 * 128 + (d ^ ((l2 & 7) << 3))]) * s_att[l2];
            }
            s_red[grp * 128 + d] = fc;
        }
        __syncthreads();
        if (t < 128)
            ST<BF>(out, OUT_FRAGCODE + bwf * D_ + t,
                   s_red[t] + s_red[128 + t] + s_red[256 + t] + s_red[384 + t]);
    }
}

// ============ qcode (64 designated blocks, 512 thr) ========================
template<bool BF>
__device__ __forceinline__ void qcode_body(int bwf, const float* ws, void* out,
                                           char* smem)
{
    u16*   s_q    = (u16*)(smem + LQ_SQ);
    float* s_n    = (float*)(smem + LQ_SN);
    float* s_part = (float*)(smem + LQ_SP);
    float* s_r4   = (float*)(smem + LQ_SR);
    int b = bwf >> 4, t = threadIdx.x;
    // stage qp for this b (128x128 bf16 = 8192 u32) coalesced, 512 thr
    {
        const u32* src = (const u32*)((const u16*)(ws + WS_QPB) + (size_t)b * 16384);
        u32* dst = (u32*)s_q;
        #pragma unroll
        for (int it = 0; it < 16; ++it) dst[t + 512 * it] = src[t + 512 * it];
    }
    float e = 0.f;
    if (t < 128) {
        e = ws[WS_E2 + bwf * 128 + t];
        float s = e;
        #pragma unroll
        for (int off = 1; off <= 32; off <<= 1) s += __shfl_xor(s, off, 64);
        if ((t & 63) == 0) s_part[t >> 6] = s;
    }
    __syncthreads();
    if (t < 128) s_n[t] = e / (s_part[0] + s_part[1] + 1e-7f);
    __syncthreads();
    {
        int d = t & 127, grp = t >> 7;   // 4 groups x 32 q each
        float qc = 0.f;
        #pragma unroll 8
        for (int qi = 0; qi < 32; ++qi) {
            int q = grp * 32 + qi;
            qc += us2f(s_q[q * 128 + d]) * s_n[q];
        }
        s_r4[grp * 128 + d] = qc;
    }
    __syncthreads();
    if (t < 128)
        ST<BF>(out, OUT_QUERYCODE + bwf * D_ + t,
               s_r4[t] + s_r4[128 + t] + s_r4[256 + t] + s_r4[384 + t]);
}

// ============ single cooperative kernel ====================================
template<bool BF>
__device__ __forceinline__ void run_all(
    const void* query, const void* fragment, const void* qmask, const void* fmask,
    const void* projB, const void* saW, const void* gatew, const void* valw,
    const void* projW, const void* qattW, const void* qfW, const void* fattW,
    float* ws, void* out, char* smem)
{
    cg::grid_group grid = cg::this_grid();
    int bx = blockIdx.x;

    // ---- stage P: weight transposes on 16 XCD-spread blocks ----
    // pu in [0,16): bx = 16*pu + (pu&7)  (one block per pu, spread over XCDs)
    if ((bx & 15) == ((bx >> 4) & 7)) {
        int pu = bx >> 4, mat = pu >> 2, kq = pu & 3;
        const void* src = (mat == 0) ? projW : (mat == 1) ? qattW : (mat == 2) ? qfW : fattW;
        u16* dst = (u16*)(ws + ((mat == 0) ? WS_PWT : (mat == 1) ? WS_QAT : (mat == 2) ? WS_W3T : WS_WFT));
        int N = (mat == 0) ? 128 : 64;
        prep_body<BF>(src, dst, (u16*)smem, N, kq * 32);
    }
    grid.sync();

    // ---- stage M: main (all 256 blocks) ----
    main_body<BF>(query, fragment, qmask, fmask, projB, saW, gatew, valw, ws, out, smem);
    grid.sync();

    // ---- stage Q: query_code on 64 XCD-spread blocks ----
    // v in [0,64): bx = 4*v + (v&3)  (one block per v, spread over XCDs)
    if ((bx & 3) == ((bx >> 2) & 3))
        qcode_body<BF>(bx >> 2, ws, out, smem);
}

__global__ __launch_bounds__(512, 2) void k_all(
    const void* query, const void* fragment, const void* qmask, const void* fmask,
    const void* projB, const void* saW, const void* gatew, const void* valw,
    const void* projW, const void* qattW, const void* qfW, const void* fattW,
    float* ws, void* out)
{
    __shared__ __align__(16) char smem[L_TOT];
    if (is_bf(qmask))
        run_all<true >(query, fragment, qmask, fmask, projB, saW, gatew, valw,
                       projW, qattW, qfW, fattW, ws, out, smem);
    else
        run_all<false>(query, fragment, qmask, fmask, projB, saW, gatew, valw,
                       projW, qattW, qfW, fattW, ws, out, smem);
}

extern "C" void kernel_launch(void* const* d_in, const int* in_sizes, int n_in,
                              void* d_out, int out_size, void* d_ws, size_t ws_size,
                              hipStream_t stream)
{
    const void* query    = d_in[0];
    const void* fragment = d_in[1];
    const void* qmask    = d_in[2];
    const void* fmask    = d_in[3];
    const void* projW    = d_in[4];
    const void* projB    = d_in[5];
    const void* saW      = d_in[6];
    const void* qattW    = d_in[7];
    const void* fattW    = d_in[8];
    const void* qfW      = d_in[9];
    const void* gatew    = d_in[10];
    const void* valw     = d_in[11];
    float* ws = (float*)d_ws;
    void* out = d_out;

    void* args[] = {
        (void*)&query, (void*)&fragment, (void*)&qmask, (void*)&fmask,
        (void*)&projB, (void*)&saW, (void*)&gatew, (void*)&valw,
        (void*)&projW, (void*)&qattW, (void*)&qfW, (void*)&fattW,
        (void*)&ws, (void*)&out
    };
    hipLaunchCooperativeKernel((void*)k_all, dim3(256), dim3(512), args, 0, stream);
}

// Round 4
// 156.958 us; speedup vs baseline: 1.1133x; 1.1133x over previous
//
#include <hip/hip_runtime.h>
#include <hip/hip_bf16.h>

#define B_   4
#define LQ_  128
#define LF_  64
#define NW_  2
#define NFR_ 8
#define E_   128
#define D_   128
#define V_   64
#define NWF_ (NW_*NFR_)            // 16

using bf16 = __hip_bfloat16;
typedef unsigned short u16;
typedef unsigned int   u32;
typedef __attribute__((ext_vector_type(8))) short  bf16x8;
typedef __attribute__((ext_vector_type(2))) float  f32x2;
typedef __attribute__((ext_vector_type(4))) float  f32x4;
typedef __attribute__((ext_vector_type(4))) u32    u32x4;

// ---- ws layout (float-index units) ----
#define WS_E2    20480    // [64][128] f32            8192 f
#define WS_QPB   28672    // [4][128][128] u16       32768 f
#define WS_CNT   61440    // [4] u32 batch counters      4 f

// ---- out layout (element units; u16 if BF out else f32) ----
#define OUT_FRAGCODE  0       // (B,NW,NFR,D)   8192
#define OUT_QUERYCODE 8192    // (B,NW,NFR,D)   8192
#define OUT_SELFATT   16384   // (B,NW,NFR,LF)  4096
#define OUT_QFGATE    20480   // (B,16,LQ)      8192
#define OUT_QUERY     28672   // (B,LQ,D)       65536

// ---- k_single LDS layout (bytes) ----
#define L_FP   0        // u16 [64][128] swizzled    16384
#define L_QP   16384    // u16 [32][128] swizzled     8192
#define L_FA   24576    // u16 [64][72] f_att         9216
#define L_QAT  33792    // u16 [32][72]               4608
#define L_SAW  38400    // f32 [128]                   512
#define L_ATT  38912    // f32 [64]                    256
#define L_RED  39168    // f32 [512]                  2048
#define L_PM   41216    // u16 [4][32][64] pmax      16384
// weights (persistent through main phases), all [n][128] u16, k-swizzled
#define L_PWT  57600    // [128][128]                32768
#define L_QATW 90368    // [64][128]                 16384
#define L_W3T  106752   // [64][128]                 16384
#define L_WFT  123136   // [64][128]                 16384
#define L_TOT  139520
// qcode tail overlay (after the handoff; weights no longer needed)
#define LT_SQ    0        // u16 [128][128]           32768
#define LT_SN    32768    // f32 [16][128]             8192
#define LT_PP    40960    // f32 [64][128]            32768

__device__ __forceinline__ float us2f(u16 v) { return __uint_as_float((u32)v << 16); }
__device__ __forceinline__ float lo2f(u32 v) { return __uint_as_float(v << 16); }
__device__ __forceinline__ float hi2f(u32 v) { return __uint_as_float(v & 0xffff0000u); }
__device__ __forceinline__ u16 f2b_raw(float f) {
    u32 u = __float_as_uint(f);
    return (u16)((u + 0x7fffu + ((u >> 16) & 1u)) >> 16);
}
__device__ __forceinline__ u32 pk2(float hi, float lo) {
    return __builtin_amdgcn_perm(__float_as_uint(hi), __float_as_uint(lo), 0x07060302u);
}
template<bool BF> __device__ __forceinline__ float LD(const void* p, int i) {
    return BF ? us2f(((const u16*)p)[i]) : ((const float*)p)[i];
}
template<bool BF> __device__ __forceinline__ void ST(void* p, int i, float v) {
    if (BF) ((u16*)p)[i] = f2b_raw(v); else ((float*)p)[i] = v;
}
template<bool BF> __device__ __forceinline__ u16 LDB(const void* p, int i) {
    return BF ? ((const u16*)p)[i] : f2b_raw(((const float*)p)[i]);
}
__device__ __forceinline__ bool is_bf(const void* qmask) {
    return ((const u16*)qmask)[0] == 0x3F80u;
}
// A-fragment (16 rows x 32 k) direct from global row-major [*,128]
template<bool BF>
__device__ __forceinline__ bf16x8 loadA(const void* x, int row, int kt, int quad) {
    int off = row * 128 + kt * 32 + quad * 8;
    if (BF) return *(const bf16x8*)((const u16*)x + off);
    f32x4 a = *(const f32x4*)((const float*)x + off);
    f32x4 c = *(const f32x4*)((const float*)x + off + 4);
    u32x4 av;
    av.x = pk2(a.y, a.x); av.y = pk2(a.w, a.z);
    av.z = pk2(c.y, c.x); av.w = pk2(c.w, c.z);
    return __builtin_bit_cast(bf16x8, av);
}

// ============ per-block weight staging: W[k][n] -> LDS W^T[n][k^swz] =======
// stg scratch overlays the main-phase regions (used before Phase A only).
template<bool BF>
__device__ __forceinline__ void stage_one(const void* src, u16* dst, u16* stg,
                                          int N, int st)
{
    int t = threadIdx.x;
    for (int i = t; i < 128 * N; i += 512) {
        int k = (N == 128) ? (i >> 7) : (i >> 6);
        int v = (N == 128) ? (i & 127) : (i & 63);
        stg[k * st + v] = LDB<BF>(src, k * N + v);
    }
    __syncthreads();
    for (int j = t; j < N * 128; j += 512) {
        int n = j >> 7, kk = j & 127;
        dst[n * 128 + (kk ^ ((n & 7) << 3))] = stg[kk * st + n];
    }
    __syncthreads();
}

// ============ qcode tail: last block of batch b does all 16 bwf ============
template<bool BF>
__device__ __forceinline__ void qcode_tail(int b, const float* ws, void* out,
                                           char* smem)
{
    u16*   s_q  = (u16*)(smem + LT_SQ);
    float* s_n  = (float*)(smem + LT_SN);
    float* s_pp = (float*)(smem + LT_PP);
    int t = threadIdx.x, lane = t & 63, w = t >> 6;
    // stage qp for this b (128x128 bf16 = 8192 u32) coalesced
    {
        const u32* src = (const u32*)((const u16*)(ws + WS_QPB) + (size_t)b * 16384);
        u32* dst = (u32*)s_q;
        #pragma unroll
        for (int it = 0; it < 16; ++it) dst[t + 512 * it] = src[t + 512 * it];
    }
    // softmax normalizers: wave w handles rows 2w, 2w+1 (16 rows total)
    #pragma unroll
    for (int rr = 0; rr < 2; ++rr) {
        int row = w * 2 + rr;                 // bwf = b*16 + row
        float e0 = ws[WS_E2 + (b * 16 + row) * 128 + lane];
        float e1 = ws[WS_E2 + (b * 16 + row) * 128 + 64 + lane];
        float s = e0 + e1;
        #pragma unroll
        for (int off = 1; off <= 32; off <<= 1) s += __shfl_xor(s, off, 64);
        float inv = 1.0f / (s + 1e-7f);
        s_n[row * 128 + lane]      = e0 * inv;
        s_n[row * 128 + 64 + lane] = e1 * inv;
    }
    __syncthreads();
    // MACs: 16 bwf x (4 grp x 32 q) x 128 d
    {
        int d = t & 127, grp = t >> 7;
        for (int bw2 = 0; bw2 < 16; ++bw2) {
            float acc = 0.f;
            #pragma unroll 8
            for (int qi = 0; qi < 32; ++qi) {
                int q = grp * 32 + qi;
                acc += us2f(s_q[q * 128 + d]) * s_n[bw2 * 128 + q];
            }
            s_pp[(bw2 * 4 + grp) * 128 + d] = acc;
        }
    }
    __syncthreads();
    for (int idx = t; idx < 2048; idx += 512) {
        int bw2 = idx >> 7, d = idx & 127;
        float v = s_pp[(bw2 * 4 + 0) * 128 + d] + s_pp[(bw2 * 4 + 1) * 128 + d]
                + s_pp[(bw2 * 4 + 2) * 128 + d] + s_pp[(bw2 * 4 + 3) * 128 + d];
        ST<BF>(out, OUT_QUERYCODE + (b * 16 + bw2) * D_ + d, v);
    }
}

// ============ k_single: 256 blocks (qt, bwf) x 512 thr =====================
// XCD-spread decode: qt = bx>>6 (4 groups of 64), bwf = bx&63.
template<bool BF>
__device__ __forceinline__ void main_body(
    const void* query, const void* fragment, const void* qmask, const void* fmask,
    const void* projB, const void* saW, const void* gatew, const void* valw,
    const void* projW, const void* qattW, const void* qfW, const void* fattW,
    float* ws, void* out, char* smem)
{
    u16*   s_fp  = (u16*)(smem + L_FP);
    u16*   s_qp  = (u16*)(smem + L_QP);
    u16*   s_fa  = (u16*)(smem + L_FA);
    u16*   s_qat = (u16*)(smem + L_QAT);
    float* s_saw = (float*)(smem + L_SAW);
    float* s_att = (float*)(smem + L_ATT);
    float* s_red = (float*)(smem + L_RED);
    u16*   s_pm  = (u16*)(smem + L_PM);
    u16*   pwt   = (u16*)(smem + L_PWT);
    u16*   qatw  = (u16*)(smem + L_QATW);
    u16*   w3t   = (u16*)(smem + L_W3T);
    u16*   wft   = (u16*)(smem + L_WFT);

    int bx = blockIdx.x;
    int qt = bx >> 6, bwf = bx & 63, b = bwf >> 4;
    int t = threadIdx.x, lane = t & 63, w = t >> 6;
    int m = lane & 15, quad = lane >> 4;
    int sk = (m & 7) << 3;
    bool do_fragatt = (qt == (bwf & 3));
    bool do_export  = ((bwf & 15) == 0);

    // ---- Phase W: stage weight transposes into LDS (scratch = smem[0..]) --
    stage_one<BF>(projW, pwt,  (u16*)smem, 128, 129);
    stage_one<BF>(qattW, qatw, (u16*)smem, 64, 65);
    stage_one<BF>(qfW,   w3t,  (u16*)smem, 64, 65);
    stage_one<BF>(fattW, wft,  (u16*)smem, 64, 65);

    // ---- Phase A: projections ----
    if (w < 4) {
        // fragment rows [w*16, w*16+16)
        bf16x8 afr[4];
        #pragma unroll
        for (int kt = 0; kt < 4; ++kt)
            afr[kt] = loadA<BF>(fragment, bwf * 64 + w * 16 + m, kt, quad);
        #pragma unroll
        for (int nt = 0; nt < 8; ++nt) {
            int n = nt * 16 + m;
            float bv = LD<BF>(projB, n);
            f32x4 acc = (f32x4){bv, bv, bv, bv};
            #pragma unroll
            for (int kt = 0; kt < 4; ++kt) {
                bf16x8 bw = *(const bf16x8*)&pwt[n * 128 + ((kt * 32 + quad * 8) ^ sk)];
                acc = __builtin_amdgcn_mfma_f32_16x16x32_bf16(afr[kt], bw, acc, 0, 0, 0);
            }
            #pragma unroll
            for (int rr = 0; rr < 4; ++rr) {
                int row = w * 16 + quad * 4 + rr;
                s_fp[row * 128 + (n ^ ((row & 7) << 3))] = f2b_raw(acc[rr]);
            }
        }
    } else if (w < 6) {
        // query rows qt*32 + (w-4)*16 + [0,16)
        int q0 = (w - 4) * 16;
        bf16x8 afq[4];
        #pragma unroll
        for (int kt = 0; kt < 4; ++kt)
            afq[kt] = loadA<BF>(query, b * 128 + qt * 32 + q0 + m, kt, quad);
        #pragma unroll
        for (int nt = 0; nt < 8; ++nt) {
            int n = nt * 16 + m;
            float bv = LD<BF>(projB, n);
            f32x4 acc = (f32x4){bv, bv, bv, bv};
            #pragma unroll
            for (int kt = 0; kt < 4; ++kt) {
                bf16x8 bw = *(const bf16x8*)&pwt[n * 128 + ((kt * 32 + quad * 8) ^ sk)];
                acc = __builtin_amdgcn_mfma_f32_16x16x32_bf16(afq[kt], bw, acc, 0, 0, 0);
            }
            #pragma unroll
            for (int rr = 0; rr < 4; ++rr) {
                int row = q0 + quad * 4 + rr;
                s_qp[row * 128 + (n ^ ((row & 7) << 3))] = f2b_raw(acc[rr]);
            }
        }
    }
    __syncthreads();

    // ---- Phase B: f_att (waves 0-3) and q_att (waves 4-5) ----
    if (w < 4) {
        bf16x8 afa[4];
        #pragma unroll
        for (int kt = 0; kt < 4; ++kt)
            afa[kt] = *(const bf16x8*)&s_fp[(w * 16 + m) * 128 + ((kt * 32 + quad * 8) ^ sk)];
        #pragma unroll
        for (int vt = 0; vt < 4; ++vt) {
            f32x4 a0 = (f32x4){0.f, 0.f, 0.f, 0.f};
            #pragma unroll
            for (int kt = 0; kt < 4; ++kt) {
                bf16x8 wk = *(const bf16x8*)&wft[(vt * 16 + m) * 128 + ((kt * 32 + quad * 8) ^ sk)];
                a0 = __builtin_amdgcn_mfma_f32_16x16x32_bf16(afa[kt], wk, a0, 0, 0, 0);
            }
            #pragma unroll
            for (int r = 0; r < 4; ++r)
                s_fa[(w * 16 + quad * 4 + r) * 72 + vt * 16 + m] = f2b_raw(a0[r]);
        }
    } else if (w < 6) {
        int q0 = (w - 4) * 16;
        bf16x8 aq[4];
        #pragma unroll
        for (int kt = 0; kt < 4; ++kt)
            aq[kt] = *(const bf16x8*)&s_qp[(q0 + m) * 128 + ((kt * 32 + quad * 8) ^ sk)];
        #pragma unroll
        for (int vt = 0; vt < 4; ++vt) {
            f32x4 a0 = (f32x4){0.f, 0.f, 0.f, 0.f};
            #pragma unroll
            for (int kt = 0; kt < 4; ++kt) {
                bf16x8 bk = *(const bf16x8*)&qatw[(vt * 16 + m) * 128 + ((kt * 32 + quad * 8) ^ sk)];
                a0 = __builtin_amdgcn_mfma_f32_16x16x32_bf16(aq[kt], bk, a0, 0, 0, 0);
            }
            #pragma unroll
            for (int r = 0; r < 4; ++r)
                s_qat[(q0 + quad * 4 + r) * 72 + vt * 16 + m] = f2b_raw(a0[r]);
        }
    }
    __syncthreads();

    // ---- Phase C: l-loop. wave = (qsub, lq) -> 16q x 16l x ALL 4 vt ----
    int qsub = w & 1, lq = w >> 1;          // lq in [0,4): 16-l quarter
    bf16x8 w3f[4][4];
    #pragma unroll
    for (int vt = 0; vt < 4; ++vt)
        #pragma unroll
        for (int kt = 0; kt < 4; ++kt)
            w3f[vt][kt] = *(const bf16x8*)&w3t[(vt * 16 + m) * 128 + ((kt * 32 + quad * 8) ^ sk)];
    f32x2 qp2[4][4];
    {
        #pragma unroll
        for (int kt = 0; kt < 4; ++kt) {
            bf16x8 aq2 = *(const bf16x8*)&s_qp[(qsub * 16 + m) * 128 + ((kt * 32 + quad * 8) ^ sk)];
            u32x4 uv = __builtin_bit_cast(u32x4, aq2);
            qp2[kt][0] = (f32x2){lo2f(uv.x), hi2f(uv.x)};
            qp2[kt][1] = (f32x2){lo2f(uv.y), hi2f(uv.y)};
            qp2[kt][2] = (f32x2){lo2f(uv.z), hi2f(uv.z)};
            qp2[kt][3] = (f32x2){lo2f(uv.w), hi2f(uv.w)};
        }
    }
    float mx[4][4];
    #pragma unroll
    for (int vt = 0; vt < 4; ++vt)
        #pragma unroll
        for (int r = 0; r < 4; ++r) mx[vt][r] = -1e30f;

    int lbase = lq * 16;
    #pragma unroll 2
    for (int li = 0; li < 16; ++li) {
        int l = lbase + li;
        int sw = (l & 7) << 3;
        bf16x8 af[4];
        #pragma unroll
        for (int kt = 0; kt < 4; ++kt) {
            u32x4 fv = *(const u32x4*)&s_fp[l * 128 + ((kt * 32 + quad * 8) ^ sw)];
            f32x2 p0 = qp2[kt][0] * (f32x2){lo2f(fv.x), hi2f(fv.x)};
            f32x2 p1 = qp2[kt][1] * (f32x2){lo2f(fv.y), hi2f(fv.y)};
            f32x2 p2 = qp2[kt][2] * (f32x2){lo2f(fv.z), hi2f(fv.z)};
            f32x2 p3 = qp2[kt][3] * (f32x2){lo2f(fv.w), hi2f(fv.w)};
            u32x4 av;
            av.x = pk2(p0.y, p0.x);
            av.y = pk2(p1.y, p1.x);
            av.z = pk2(p2.y, p2.x);
            av.w = pk2(p3.y, p3.x);
            af[kt] = __builtin_bit_cast(bf16x8, av);
        }
        #pragma unroll
        for (int vt = 0; vt < 4; ++vt) {
            float fa = us2f(s_fa[l * 72 + vt * 16 + m]);
            f32x4 acc = (f32x4){fa, fa, fa, fa};
            #pragma unroll
            for (int kt = 0; kt < 4; ++kt)
                acc = __builtin_amdgcn_mfma_f32_16x16x32_bf16(af[kt], w3f[vt][kt], acc, 0, 0, 0);
            #pragma unroll
            for (int r = 0; r < 4; ++r) mx[vt][r] = fmaxf(mx[vt][r], acc[r]);
        }
    }
    // partial maxes to dedicated s_pm (bank-swizzled)
    #pragma unroll
    for (int vt = 0; vt < 4; ++vt)
        #pragma unroll
        for (int r = 0; r < 4; ++r) {
            int q = qsub * 16 + quad * 4 + r;
            s_pm[(lq * 32 + q) * 64 + ((vt * 16 + m) ^ (((q >> 2) & 3) << 4))] = f2b_raw(mx[vt][r]);
        }
    __syncthreads();

    // ---- Phase D: gate / e2 epilogue (q = t>>4 in [0,32), vg = t&15) ----
    {
        int q = t >> 4, vg = t & 15;
        int gq = qt * 32 + q;
        int swq = ((q >> 2) & 3) << 4;
        float gp = 0.f, ep = 0.f;
        #pragma unroll
        for (int jj = 0; jj < 4; ++jj) {
            int v = vg * 4 + jj;
            int c = v ^ swq;
            float m01 = fmaxf(us2f(s_pm[q * 64 + c]),        us2f(s_pm[(32 + q) * 64 + c]));
            float m23 = fmaxf(us2f(s_pm[(64 + q) * 64 + c]), us2f(s_pm[(96 + q) * 64 + c]));
            float qf = fmaxf(m01, m23) + us2f(s_qat[q * 72 + v]);
            gp += qf * LD<BF>(gatew, v);
            ep += qf * LD<BF>(valw, v);
        }
        #pragma unroll
        for (int off = 1; off <= 8; off <<= 1) {
            gp += __shfl_xor(gp, off, 64);
            ep += __shfl_xor(ep, off, 64);
        }
        if (vg == 0) {
            float qm = LD<BF>(qmask, b * 128 + gq);
            float g = (1.0f / (1.0f + expf(-gp))) * qm;
            ST<BF>(out, OUT_QFGATE + bwf * LQ_ + gq, g);
            ws[WS_E2 + bwf * 128 + gq] = expf(ep) * qm;
        }
    }

    // ---- qp export (bwf%16==0 blocks; each exports its own 32 q rows) ----
    if (do_export) {
        u16* qpb = (u16*)(ws + WS_QPB);
        #pragma unroll
        for (int it = 0; it < 8; ++it) {
            int i = t + 512 * it;              // 4096 = 32*128
            int row = i >> 7, col = i & 127;
            u16 raw = s_qp[row * 128 + (col ^ ((row & 7) << 3))];
            int gr = b * 128 + qt * 32 + row;
            ST<BF>(out, OUT_QUERY + gr * 128 + col, us2f(raw));
            qpb[gr * 128 + col] = raw;
        }
    }

    // ---- fragment self-attention + frag_code (XCD-spread assignment) ----
    if (do_fragatt) {
        if (t < 128) s_saw[t] = LD<BF>(saW, ((bwf >> 3) & 1) * 128 + t);
        __syncthreads();
        {
            int l = t >> 3, j8 = t & 7;
            int swz = (l & 7) << 3;
            float p = 0.f;
            #pragma unroll
            for (int seg = 0; seg < 2; ++seg) {
                int koff = j8 * 16 + seg * 8;
                u32x4 fv = *(const u32x4*)&s_fp[l * 128 + (koff ^ swz)];
                const float* swp = &s_saw[koff];
                p += lo2f(fv.x) * swp[0] + hi2f(fv.x) * swp[1]
                   + lo2f(fv.y) * swp[2] + hi2f(fv.y) * swp[3]
                   + lo2f(fv.z) * swp[4] + hi2f(fv.z) * swp[5]
                   + lo2f(fv.w) * swp[6] + hi2f(fv.w) * swp[7];
            }
            p += __shfl_xor(p, 1, 64);
            p += __shfl_xor(p, 2, 64);
            p += __shfl_xor(p, 4, 64);
            if (j8 == 0) s_att[l] = expf(p) * LD<BF>(fmask, bwf * LF_ + l);
        }
        __syncthreads();
        if (t < 64) {
            float e = s_att[t], s = e;
            #pragma unroll
            for (int off = 1; off <= 32; off <<= 1) s += __shfl_xor(s, off, 64);
            float nrm = e / (s + 1e-7f);
            s_att[t] = nrm;
            ST<BF>(out, OUT_SELFATT + bwf * LF_ + t, nrm);
        }
        __syncthreads();
        {
            int d = t & 127, grp = t >> 7;
            float fc = 0.f;
            #pragma unroll
            for (int li2 = 0; li2 < 16; ++li2) {
                int l2 = grp * 16 + li2;
                fc += us2f(s_fp[l2 * 128 + (d ^ ((l2 & 7) << 3))]) * s_att[l2];
            }
            s_red[grp * 128 + d] = fc;
        }
        __syncthreads();
        if (t < 128)
            ST<BF>(out, OUT_FRAGCODE + bwf * D_ + t,
                   s_red[t] + s_red[128 + t] + s_red[256 + t] + s_red[384 + t]);
    }

    // ---- handoff: last block of batch b computes query_code for all 16 bwf
    __threadfence();                 // release this block's ws/out writes
    __syncthreads();
    if (t == 0) {
        u32* cnt = (u32*)(ws + WS_CNT);
        u32 old = __hip_atomic_fetch_add(&cnt[b], 1u, __ATOMIC_ACQ_REL,
                                         __HIP_MEMORY_SCOPE_AGENT);
        *(volatile int*)(smem + L_RED) = (old == 63u) ? 1 : 0;
    }
    __syncthreads();
    int amlast = *(volatile int*)(smem + L_RED);
    if (!amlast) return;
    __threadfence();                 // acquire for all threads of tail block
    __syncthreads();
    qcode_tail<BF>(b, ws, out, smem);
}

__global__ __launch_bounds__(512, 2) void k_single(
    const void* query, const void* fragment, const void* qmask, const void* fmask,
    const void* projB, const void* saW, const void* gatew, const void* valw,
    const void* projW, const void* qattW, const void* qfW, const void* fattW,
    float* ws, void* out)
{
    __shared__ __align__(16) char smem[L_TOT];
    if (is_bf(qmask))
        main_body<true >(query, fragment, qmask, fmask, projB, saW, gatew, valw,
                         projW, qattW, qfW, fattW, ws, out, smem);
    else
        main_body<false>(query, fragment, qmask, fmask, projB, saW, gatew, valw,
                         projW, qattW, qfW, fattW, ws, out, smem);
}

extern "C" void kernel_launch(void* const* d_in, const int* in_sizes, int n_in,
                              void* d_out, int out_size, void* d_ws, size_t ws_size,
                              hipStream_t stream)
{
    const void* query    = d_in[0];
    const void* fragment = d_in[1];
    const void* qmask    = d_in[2];
    const void* fmask    = d_in[3];
    const void* projW    = d_in[4];
    const void* projB    = d_in[5];
    const void* saW      = d_in[6];
    const void* qattW    = d_in[7];
    const void* fattW    = d_in[8];
    const void* qfW      = d_in[9];
    const void* gatew    = d_in[10];
    const void* valw     = d_in[11];
    float* ws = (float*)d_ws;

    // zero the 4 per-batch handoff counters (ws is poisoned each iteration)
    hipMemsetAsync((char*)d_ws + WS_CNT * sizeof(float), 0, 4 * sizeof(u32), stream);

    hipLaunchKernelGGL(k_single, dim3(256), dim3(512), 0, stream,
                       query, fragment, qmask, fmask, projB, saW, gatew, valw,
                       projW, qattW, qfW, fattW, ws, d_out);
}

// Round 6
// 102.441 us; speedup vs baseline: 1.7057x; 1.5322x over previous
//
#include <hip/hip_runtime.h>
#include <hip/hip_bf16.h>

#define B_   4
#define LQ_  128
#define LF_  64
#define NW_  2
#define NFR_ 8
#define E_   128
#define D_   128
#define V_   64
#define NWF_ (NW_*NFR_)            // 16

using bf16 = __hip_bfloat16;
typedef unsigned short u16;
typedef unsigned int   u32;
typedef __attribute__((ext_vector_type(8))) short  bf16x8;
typedef __attribute__((ext_vector_type(2))) float  f32x2;
typedef __attribute__((ext_vector_type(4))) float  f32x4;
typedef __attribute__((ext_vector_type(4))) u32    u32x4;
typedef __attribute__((ext_vector_type(4))) unsigned short u16x4;

// ---- ws layout (float-index units) ----
#define WS_QCN   0        // [4 qt][64 bwf][128 d] f32 partial numerators 32768 f
#define WS_QCS   32768    // [4 qt][64 bwf] f32 partial denominators       256 f

// ---- out layout (element units; u16 if BF out else f32) ----
#define OUT_FRAGCODE  0       // (B,NW,NFR,D)   8192
#define OUT_QUERYCODE 8192    // (B,NW,NFR,D)   8192
#define OUT_SELFATT   16384   // (B,NW,NFR,LF)  4096
#define OUT_QFGATE    20480   // (B,16,LQ)      8192
#define OUT_QUERY     28672   // (B,LQ,D)       65536

// ---- k_main LDS layout (bytes) ----
#define L_FP   0        // u16 [64][128] swizzled    16384
#define L_QP   16384    // u16 [32][128] swizzled     8192
#define L_FA   24576    // u16 [64][72] f_att         9216
#define L_QAT  33792    // u16 [32][72]               4608
#define L_SAW  38400    // f32 [128]                   512
#define L_ATT  38912    // f32 [64]                    256
#define L_RED  39168    // f32 [512]                  2048
#define L_PM   41216    // u16 [4][32][64] pmax      16384
// weights (persistent through main phases), all [n][128] u16, k-swizzled
#define L_PWT  57600    // [128][128]                32768
#define L_QATW 90368    // [64][128]                 16384
#define L_W3T  106752   // [64][128]                 16384
#define L_WFT  123136   // [64][128]                 16384
#define L_E2   139520   // f32 [32] e2 values          128
#define L_TOT  139648

__device__ __forceinline__ float us2f(u16 v) { return __uint_as_float((u32)v << 16); }
__device__ __forceinline__ float lo2f(u32 v) { return __uint_as_float(v << 16); }
__device__ __forceinline__ float hi2f(u32 v) { return __uint_as_float(v & 0xffff0000u); }
__device__ __forceinline__ u16 f2b_raw(float f) {
    u32 u = __float_as_uint(f);
    return (u16)((u + 0x7fffu + ((u >> 16) & 1u)) >> 16);
}
__device__ __forceinline__ u32 pk2(float hi, float lo) {
    return __builtin_amdgcn_perm(__float_as_uint(hi), __float_as_uint(lo), 0x07060302u);
}
template<bool BF> __device__ __forceinline__ float LD(const void* p, int i) {
    return BF ? us2f(((const u16*)p)[i]) : ((const float*)p)[i];
}
template<bool BF> __device__ __forceinline__ void ST(void* p, int i, float v) {
    if (BF) ((u16*)p)[i] = f2b_raw(v); else ((float*)p)[i] = v;
}
__device__ __forceinline__ bool is_bf(const void* qmask) {
    return ((const u16*)qmask)[0] == 0x3F80u;
}
// A-fragment (16 rows x 32 k) direct from global row-major [*,128]
template<bool BF>
__device__ __forceinline__ bf16x8 loadA(const void* x, int row, int kt, int quad) {
    int off = row * 128 + kt * 32 + quad * 8;
    if (BF) return *(const bf16x8*)((const u16*)x + off);
    f32x4 a = *(const f32x4*)((const float*)x + off);
    f32x4 c = *(const f32x4*)((const float*)x + off + 4);
    u32x4 av;
    av.x = pk2(a.y, a.x); av.y = pk2(a.w, a.z);
    av.z = pk2(c.y, c.x); av.w = pk2(c.w, c.z);
    return __builtin_bit_cast(bf16x8, av);
}

// ============ per-block weight staging: W[k][N] -> LDS W^T[n][k^swz] =======
// Vectorized: pass-1 f32x4/u16x4 coalesced global loads into stg[k][n]
// (stride st = N+1); pass-2 LDS transpose into dst with the same XOR swizzle
// the consumers use (row n, col k: k ^ ((n&7)<<3)). stg overlays the
// main-phase LDS regions (used strictly before Phase A).
template<bool BF>
__device__ __forceinline__ void stage_w(const void* src, u16* dst, u16* stg,
                                        int N, int st)
{
    int t = threadIdx.x;
    int items1 = (128 * N) >> 2;
    for (int i = t; i < items1; i += 512) {
        int e = i << 2;                       // element index (consecutive)
        u16 a, b, c, d;
        if (BF) {
            u16x4 v = *(const u16x4*)((const u16*)src + e);
            a = v.x; b = v.y; c = v.z; d = v.w;
        } else {
            f32x4 v = *(const f32x4*)((const float*)src + e);
            a = f2b_raw(v.x); b = f2b_raw(v.y); c = f2b_raw(v.z); d = f2b_raw(v.w);
        }
        int k = (N == 128) ? (e >> 7) : (e >> 6);
        int vv = (N == 128) ? (e & 127) : (e & 63);
        stg[k * st + vv]     = a;
        stg[k * st + vv + 1] = b;
        stg[k * st + vv + 2] = c;
        stg[k * st + vv + 3] = d;
    }
    __syncthreads();
    int items2 = (N * 128) >> 2;
    for (int j = t; j < items2; j += 512) {
        int n = j >> 5, k4 = (j & 31) << 2;
        u16x4 o;
        o.x = stg[(k4 + 0) * st + n];
        o.y = stg[(k4 + 1) * st + n];
        o.z = stg[(k4 + 2) * st + n];
        o.w = stg[(k4 + 3) * st + n];
        *(u16x4*)&dst[n * 128 + (k4 ^ ((n & 7) << 3))] = o;
    }
    __syncthreads();
}

// ============ k_main: 256 blocks (qt, bwf) x 512 thr =======================
// XCD-spread decode: qt = bx>>6 (4 groups of 64), bwf = bx&63.
template<bool BF>
__device__ __forceinline__ void main_body(
    const void* query, const void* fragment, const void* qmask, const void* fmask,
    const void* projB, const void* saW, const void* gatew, const void* valw,
    const void* projW, const void* qattW, const void* qfW, const void* fattW,
    float* ws, void* out, char* smem)
{
    u16*   s_fp  = (u16*)(smem + L_FP);
    u16*   s_qp  = (u16*)(smem + L_QP);
    u16*   s_fa  = (u16*)(smem + L_FA);
    u16*   s_qat = (u16*)(smem + L_QAT);
    float* s_saw = (float*)(smem + L_SAW);
    float* s_att = (float*)(smem + L_ATT);
    float* s_red = (float*)(smem + L_RED);
    u16*   s_pm  = (u16*)(smem + L_PM);
    u16*   pwt   = (u16*)(smem + L_PWT);
    u16*   qatw  = (u16*)(smem + L_QATW);
    u16*   w3t   = (u16*)(smem + L_W3T);
    u16*   wft   = (u16*)(smem + L_WFT);
    float* s_e2  = (float*)(smem + L_E2);

    int bx = blockIdx.x;
    int qt = bx >> 6, bwf = bx & 63, b = bwf >> 4;
    int t = threadIdx.x, lane = t & 63, w = t >> 6;
    int m = lane & 15, quad = lane >> 4;
    int sk = (m & 7) << 3;
    bool do_fragatt = (qt == (bwf & 3));
    bool do_export  = ((bwf & 15) == 0);

    // ---- Phase W: stage weight transposes into LDS ----
    stage_w<BF>(projW, pwt,  (u16*)smem, 128, 129);
    stage_w<BF>(qattW, qatw, (u16*)smem, 64, 65);
    stage_w<BF>(qfW,   w3t,  (u16*)smem, 64, 65);
    stage_w<BF>(fattW, wft,  (u16*)smem, 64, 65);

    // ---- Phase A: projections ----
    if (w < 4) {
        // fragment rows [w*16, w*16+16)
        bf16x8 afr[4];
        #pragma unroll
        for (int kt = 0; kt < 4; ++kt)
            afr[kt] = loadA<BF>(fragment, bwf * 64 + w * 16 + m, kt, quad);
        #pragma unroll
        for (int nt = 0; nt < 8; ++nt) {
            int n = nt * 16 + m;
            float bv = LD<BF>(projB, n);
            f32x4 acc = (f32x4){bv, bv, bv, bv};
            #pragma unroll
            for (int kt = 0; kt < 4; ++kt) {
                bf16x8 bw = *(const bf16x8*)&pwt[n * 128 + ((kt * 32 + quad * 8) ^ sk)];
                acc = __builtin_amdgcn_mfma_f32_16x16x32_bf16(afr[kt], bw, acc, 0, 0, 0);
            }
            #pragma unroll
            for (int rr = 0; rr < 4; ++rr) {
                int row = w * 16 + quad * 4 + rr;
                s_fp[row * 128 + (n ^ ((row & 7) << 3))] = f2b_raw(acc[rr]);
            }
        }
    } else if (w < 6) {
        // query rows qt*32 + (w-4)*16 + [0,16)
        int q0 = (w - 4) * 16;
        bf16x8 afq[4];
        #pragma unroll
        for (int kt = 0; kt < 4; ++kt)
            afq[kt] = loadA<BF>(query, b * 128 + qt * 32 + q0 + m, kt, quad);
        #pragma unroll
        for (int nt = 0; nt < 8; ++nt) {
            int n = nt * 16 + m;
            float bv = LD<BF>(projB, n);
            f32x4 acc = (f32x4){bv, bv, bv, bv};
            #pragma unroll
            for (int kt = 0; kt < 4; ++kt) {
                bf16x8 bw = *(const bf16x8*)&pwt[n * 128 + ((kt * 32 + quad * 8) ^ sk)];
                acc = __builtin_amdgcn_mfma_f32_16x16x32_bf16(afq[kt], bw, acc, 0, 0, 0);
            }
            #pragma unroll
            for (int rr = 0; rr < 4; ++rr) {
                int row = q0 + quad * 4 + rr;
                s_qp[row * 128 + (n ^ ((row & 7) << 3))] = f2b_raw(acc[rr]);
            }
        }
    }
    __syncthreads();

    // ---- Phase B: f_att (waves 0-3) and q_att (waves 4-5) ----
    if (w < 4) {
        bf16x8 afa[4];
        #pragma unroll
        for (int kt = 0; kt < 4; ++kt)
            afa[kt] = *(const bf16x8*)&s_fp[(w * 16 + m) * 128 + ((kt * 32 + quad * 8) ^ sk)];
        #pragma unroll
        for (int vt = 0; vt < 4; ++vt) {
            f32x4 a0 = (f32x4){0.f, 0.f, 0.f, 0.f};
            #pragma unroll
            for (int kt = 0; kt < 4; ++kt) {
                bf16x8 wk = *(const bf16x8*)&wft[(vt * 16 + m) * 128 + ((kt * 32 + quad * 8) ^ sk)];
                a0 = __builtin_amdgcn_mfma_f32_16x16x32_bf16(afa[kt], wk, a0, 0, 0, 0);
            }
            #pragma unroll
            for (int r = 0; r < 4; ++r)
                s_fa[(w * 16 + quad * 4 + r) * 72 + vt * 16 + m] = f2b_raw(a0[r]);
        }
    } else if (w < 6) {
        int q0 = (w - 4) * 16;
        bf16x8 aq[4];
        #pragma unroll
        for (int kt = 0; kt < 4; ++kt)
            aq[kt] = *(const bf16x8*)&s_qp[(q0 + m) * 128 + ((kt * 32 + quad * 8) ^ sk)];
        #pragma unroll
        for (int vt = 0; vt < 4; ++vt) {
            f32x4 a0 = (f32x4){0.f, 0.f, 0.f, 0.f};
            #pragma unroll
            for (int kt = 0; kt < 4; ++kt) {
                bf16x8 bk = *(const bf16x8*)&qatw[(vt * 16 + m) * 128 + ((kt * 32 + quad * 8) ^ sk)];
                a0 = __builtin_amdgcn_mfma_f32_16x16x32_bf16(aq[kt], bk, a0, 0, 0, 0);
            }
            #pragma unroll
            for (int r = 0; r < 4; ++r)
                s_qat[(q0 + quad * 4 + r) * 72 + vt * 16 + m] = f2b_raw(a0[r]);
        }
    }
    __syncthreads();

    // ---- Phase C: l-loop. wave = (qsub, lq) -> 16q x 16l x ALL 4 vt ----
    int qsub = w & 1, lq = w >> 1;          // lq in [0,4): 16-l quarter
    bf16x8 w3f[4][4];
    #pragma unroll
    for (int vt = 0; vt < 4; ++vt)
        #pragma unroll
        for (int kt = 0; kt < 4; ++kt)
            w3f[vt][kt] = *(const bf16x8*)&w3t[(vt * 16 + m) * 128 + ((kt * 32 + quad * 8) ^ sk)];
    f32x2 qp2[4][4];
    {
        #pragma unroll
        for (int kt = 0; kt < 4; ++kt) {
            bf16x8 aq2 = *(const bf16x8*)&s_qp[(qsub * 16 + m) * 128 + ((kt * 32 + quad * 8) ^ sk)];
            u32x4 uv = __builtin_bit_cast(u32x4, aq2);
            qp2[kt][0] = (f32x2){lo2f(uv.x), hi2f(uv.x)};
            qp2[kt][1] = (f32x2){lo2f(uv.y), hi2f(uv.y)};
            qp2[kt][2] = (f32x2){lo2f(uv.z), hi2f(uv.z)};
            qp2[kt][3] = (f32x2){lo2f(uv.w), hi2f(uv.w)};
        }
    }
    float mx[4][4];
    #pragma unroll
    for (int vt = 0; vt < 4; ++vt)
        #pragma unroll
        for (int r = 0; r < 4; ++r) mx[vt][r] = -1e30f;

    int lbase = lq * 16;
    #pragma unroll 2
    for (int li = 0; li < 16; ++li) {
        int l = lbase + li;
        int sw = (l & 7) << 3;
        bf16x8 af[4];
        #pragma unroll
        for (int kt = 0; kt < 4; ++kt) {
            u32x4 fv = *(const u32x4*)&s_fp[l * 128 + ((kt * 32 + quad * 8) ^ sw)];
            f32x2 p0 = qp2[kt][0] * (f32x2){lo2f(fv.x), hi2f(fv.x)};
            f32x2 p1 = qp2[kt][1] * (f32x2){lo2f(fv.y), hi2f(fv.y)};
            f32x2 p2 = qp2[kt][2] * (f32x2){lo2f(fv.z), hi2f(fv.z)};
            f32x2 p3 = qp2[kt][3] * (f32x2){lo2f(fv.w), hi2f(fv.w)};
            u32x4 av;
            av.x = pk2(p0.y, p0.x);
            av.y = pk2(p1.y, p1.x);
            av.z = pk2(p2.y, p2.x);
            av.w = pk2(p3.y, p3.x);
            af[kt] = __builtin_bit_cast(bf16x8, av);
        }
        #pragma unroll
        for (int vt = 0; vt < 4; ++vt) {
            float fa = us2f(s_fa[l * 72 + vt * 16 + m]);
            f32x4 acc = (f32x4){fa, fa, fa, fa};
            #pragma unroll
            for (int kt = 0; kt < 4; ++kt)
                acc = __builtin_amdgcn_mfma_f32_16x16x32_bf16(af[kt], w3f[vt][kt], acc, 0, 0, 0);
            #pragma unroll
            for (int r = 0; r < 4; ++r) mx[vt][r] = fmaxf(mx[vt][r], acc[r]);
        }
    }
    // partial maxes to dedicated s_pm (bank-swizzled)
    #pragma unroll
    for (int vt = 0; vt < 4; ++vt)
        #pragma unroll
        for (int r = 0; r < 4; ++r) {
            int q = qsub * 16 + quad * 4 + r;
            s_pm[(lq * 32 + q) * 64 + ((vt * 16 + m) ^ (((q >> 2) & 3) << 4))] = f2b_raw(mx[vt][r]);
        }
    __syncthreads();

    // ---- Phase D: gate / e2 epilogue (q = t>>4 in [0,32), vg = t&15) ----
    {
        int q = t >> 4, vg = t & 15;
        int gq = qt * 32 + q;
        int swq = ((q >> 2) & 3) << 4;
        float gp = 0.f, ep = 0.f;
        #pragma unroll
        for (int jj = 0; jj < 4; ++jj) {
            int v = vg * 4 + jj;
            int c = v ^ swq;
            float m01 = fmaxf(us2f(s_pm[q * 64 + c]),        us2f(s_pm[(32 + q) * 64 + c]));
            float m23 = fmaxf(us2f(s_pm[(64 + q) * 64 + c]), us2f(s_pm[(96 + q) * 64 + c]));
            float qf = fmaxf(m01, m23) + us2f(s_qat[q * 72 + v]);
            gp += qf * LD<BF>(gatew, v);
            ep += qf * LD<BF>(valw, v);
        }
        #pragma unroll
        for (int off = 1; off <= 8; off <<= 1) {
            gp += __shfl_xor(gp, off, 64);
            ep += __shfl_xor(ep, off, 64);
        }
        if (vg == 0) {
            float qm = LD<BF>(qmask, b * 128 + gq);
            float g = (1.0f / (1.0f + expf(-gp))) * qm;
            ST<BF>(out, OUT_QFGATE + bwf * LQ_ + gq, g);
            s_e2[q] = expf(ep) * qm;
        }
    }
    __syncthreads();

    // ---- Phase E: query_code partials (linear in e2, no normalization) ----
    // N_qt[d] = sum_{q in this block's 32} qp[q][d] * e2[q];  S_qt = sum e2.
    {
        int d = t & 127, grp = t >> 7;   // 4 groups x 8 q each
        float pa = 0.f;
        #pragma unroll
        for (int qi = 0; qi < 8; ++qi) {
            int q = grp * 8 + qi;
            pa += us2f(s_qp[q * 128 + (d ^ ((q & 7) << 3))]) * s_e2[q];
        }
        s_red[grp * 128 + d] = pa;
    }
    __syncthreads();
    if (t < 128)
        ws[WS_QCN + (qt * 64 + bwf) * 128 + t] =
            s_red[t] + s_red[128 + t] + s_red[256 + t] + s_red[384 + t];
    if (t == 0) {
        float S = 0.f;
        #pragma unroll
        for (int q = 0; q < 32; ++q) S += s_e2[q];
        ws[WS_QCS + qt * 64 + bwf] = S;
    }
    __syncthreads();   // s_red reused by fragatt below

    // ---- qp export (bwf%16==0 blocks; each exports its own 32 q rows) ----
    if (do_export) {
        #pragma unroll
        for (int it = 0; it < 8; ++it) {
            int i = t + 512 * it;              // 4096 = 32*128
            int row = i >> 7, col = i & 127;
            u16 raw = s_qp[row * 128 + (col ^ ((row & 7) << 3))];
            int gr = b * 128 + qt * 32 + row;
            ST<BF>(out, OUT_QUERY + gr * 128 + col, us2f(raw));
        }
    }

    // ---- fragment self-attention + frag_code (XCD-spread assignment) ----
    if (do_fragatt) {
        if (t < 128) s_saw[t] = LD<BF>(saW, ((bwf >> 3) & 1) * 128 + t);
        __syncthreads();
        {
            int l = t >> 3, j8 = t & 7;
            int swz = (l & 7) << 3;
            float p = 0.f;
            #pragma unroll
            for (int seg = 0; seg < 2; ++seg) {
                int koff = j8 * 16 + seg * 8;
                u32x4 fv = *(const u32x4*)&s_fp[l * 128 + (koff ^ swz)];
                const float* swp = &s_saw[koff];
                p += lo2f(fv.x) * swp[0] + hi2f(fv.x) * swp[1]
                   + lo2f(fv.y) * swp[2] + hi2f(fv.y) * swp[3]
                   + lo2f(fv.z) * swp[4] + hi2f(fv.z) * swp[5]
                   + lo2f(fv.w) * swp[6] + hi2f(fv.w) * swp[7];
            }
            p += __shfl_xor(p, 1, 64);
            p += __shfl_xor(p, 2, 64);
            p += __shfl_xor(p, 4, 64);
            if (j8 == 0) s_att[l] = expf(p) * LD<BF>(fmask, bwf * LF_ + l);
        }
        __syncthreads();
        if (t < 64) {
            float e = s_att[t], s = e;
            #pragma unroll
            for (int off = 1; off <= 32; off <<= 1) s += __shfl_xor(s, off, 64);
            float nrm = e / (s + 1e-7f);
            s_att[t] = nrm;
            ST<BF>(out, OUT_SELFATT + bwf * LF_ + t, nrm);
        }
        __syncthreads();
        {
            int d = t & 127, grp = t >> 7;
            float fc = 0.f;
            #pragma unroll
            for (int li2 = 0; li2 < 16; ++li2) {
                int l2 = grp * 16 + li2;
                fc += us2f(s_fp[l2 * 128 + (d ^ ((l2 & 7) << 3))]) * s_att[l2];
            }
            s_red[grp * 128 + d] = fc;
        }
        __syncthreads();
        if (t < 128)
            ST<BF>(out, OUT_FRAGCODE + bwf * D_ + t,
                   s_red[t] + s_red[128 + t] + s_red[256 + t] + s_red[384 + t]);
    }
}

__global__ __launch_bounds__(512, 2) void k_main2(
    const void* query, const void* fragment, const void* qmask, const void* fmask,
    const void* projB, const void* saW, const void* gatew, const void* valw,
    const void* projW, const void* qattW, const void* qfW, const void* fattW,
    float* ws, void* out)
{
    __shared__ __align__(16) char smem[L_TOT];
    if (is_bf(qmask))
        main_body<true >(query, fragment, qmask, fmask, projB, saW, gatew, valw,
                         projW, qattW, qfW, fattW, ws, out, smem);
    else
        main_body<false>(query, fragment, qmask, fmask, projB, saW, gatew, valw,
                         projW, qattW, qfW, fattW, ws, out, smem);
}

// ============ k_combine: 64 blocks x 128 thr — sum 4 qt partials ==========
template<bool BF>
__device__ __forceinline__ void combine_body(const float* ws, void* out)
{
    int bwf = blockIdx.x, t = threadIdx.x;
    float den = ws[WS_QCS + bwf] + ws[WS_QCS + 64 + bwf]
              + ws[WS_QCS + 128 + bwf] + ws[WS_QCS + 192 + bwf] + 1e-7f;
    float num = ws[WS_QCN + (bwf) * 128 + t]
              + ws[WS_QCN + (64 + bwf) * 128 + t]
              + ws[WS_QCN + (128 + bwf) * 128 + t]
              + ws[WS_QCN + (192 + bwf) * 128 + t];
    ST<BF>(out, OUT_QUERYCODE + bwf * D_ + t, num / den);
}
__global__ __launch_bounds__(128) void k_combine(const void* qmask, const float* ws, void* out)
{
    if (is_bf(qmask)) combine_body<true >(ws, out);
    else              combine_body<false>(ws, out);
}

extern "C" void kernel_launch(void* const* d_in, const int* in_sizes, int n_in,
                              void* d_out, int out_size, void* d_ws, size_t ws_size,
                              hipStream_t stream)
{
    const void* query    = d_in[0];
    const void* fragment = d_in[1];
    const void* qmask    = d_in[2];
    const void* fmask    = d_in[3];
    const void* projW    = d_in[4];
    const void* projB    = d_in[5];
    const void* saW      = d_in[6];
    const void* qattW    = d_in[7];
    const void* fattW    = d_in[8];
    const void* qfW      = d_in[9];
    const void* gatew    = d_in[10];
    const void* valw     = d_in[11];
    float* ws = (float*)d_ws;

    hipLaunchKernelGGL(k_main2, dim3(256), dim3(512), 0, stream,
                       query, fragment, qmask, fmask, projB, saW, gatew, valw,
                       projW, qattW, qfW, fattW, ws, d_out);
    hipLaunchKernelGGL(k_combine, dim3(B_ * NWF_), dim3(128), 0, stream,
                       qmask, ws, d_out);
}

// Round 9
// 102.405 us; speedup vs baseline: 1.7063x; 1.0004x over previous
//
#include <hip/hip_runtime.h>
#include <hip/hip_bf16.h>

#define B_   4
#define LQ_  128
#define LF_  64
#define NW_  2
#define NFR_ 8
#define E_   128
#define D_   128
#define V_   64
#define NWF_ (NW_*NFR_)            // 16

using bf16 = __hip_bfloat16;
typedef unsigned short u16;
typedef unsigned int   u32;
typedef __attribute__((ext_vector_type(8))) short  bf16x8;
typedef __attribute__((ext_vector_type(2))) float  f32x2;
typedef __attribute__((ext_vector_type(4))) float  f32x4;
typedef __attribute__((ext_vector_type(4))) u32    u32x4;
typedef __attribute__((ext_vector_type(4))) unsigned short u16x4;

// ---- ws layout (float-index units) ----
#define WS_QCN   0        // [4 qt][64 bwf][128 d] f32 partial numerators 32768 f
#define WS_QCS   32768    // [4 qt][64 bwf] f32 partial denominators       256 f

// ---- out layout (element units; u16 if BF out else f32) ----
#define OUT_FRAGCODE  0       // (B,NW,NFR,D)   8192
#define OUT_QUERYCODE 8192    // (B,NW,NFR,D)   8192
#define OUT_SELFATT   16384   // (B,NW,NFR,LF)  4096
#define OUT_QFGATE    20480   // (B,16,LQ)      8192
#define OUT_QUERY     28672   // (B,LQ,D)       65536

// ---- k_main LDS layout (bytes) ----
#define L_FP   0        // u16 [64][128] swizzled    16384
#define L_QP   16384    // u16 [32][128] swizzled     8192
#define L_FA   24576    // u16 [64][72] f_att         9216
#define L_QAT  33792    // u16 [32][72]               4608
#define L_SAW  38400    // f32 [128]                   512
#define L_ATT  38912    // f32 [64]                    256
#define L_RED  39168    // f32 [512]                  2048
#define L_PM   41216    // u16 [4][32][64] pmax      16384
// weights (persistent through main phases), all [n][128] u16, k-swizzled
#define L_PWT  57600    // [128][128]                32768
#define L_QATW 90368    // [64][128]                 16384
#define L_W3T  106752   // [64][128]                 16384
#define L_WFT  123136   // [64][128]                 16384
#define L_E2   139520   // f32 [32] e2 values          128
#define L_TOT  139648

__device__ __forceinline__ float us2f(u16 v) { return __uint_as_float((u32)v << 16); }
__device__ __forceinline__ float lo2f(u32 v) { return __uint_as_float(v << 16); }
__device__ __forceinline__ float hi2f(u32 v) { return __uint_as_float(v & 0xffff0000u); }
__device__ __forceinline__ u16 f2b_raw(float f) {
    u32 u = __float_as_uint(f);
    return (u16)((u + 0x7fffu + ((u >> 16) & 1u)) >> 16);
}
__device__ __forceinline__ u32 pk2(float hi, float lo) {
    return __builtin_amdgcn_perm(__float_as_uint(hi), __float_as_uint(lo), 0x07060302u);
}
template<bool BF> __device__ __forceinline__ float LD(const void* p, int i) {
    return BF ? us2f(((const u16*)p)[i]) : ((const float*)p)[i];
}
template<bool BF> __device__ __forceinline__ void ST(void* p, int i, float v) {
    if (BF) ((u16*)p)[i] = f2b_raw(v); else ((float*)p)[i] = v;
}
__device__ __forceinline__ bool is_bf(const void* qmask) {
    return ((const u16*)qmask)[0] == 0x3F80u;
}
// A-fragment (16 rows x 32 k) direct from global row-major [*,128]
template<bool BF>
__device__ __forceinline__ bf16x8 loadA(const void* x, int row, int kt, int quad) {
    int off = row * 128 + kt * 32 + quad * 8;
    if (BF) return *(const bf16x8*)((const u16*)x + off);
    f32x4 a = *(const f32x4*)((const float*)x + off);
    f32x4 c = *(const f32x4*)((const float*)x + off + 4);
    u32x4 av;
    av.x = pk2(a.y, a.x); av.y = pk2(a.w, a.z);
    av.z = pk2(c.y, c.x); av.w = pk2(c.w, c.z);
    return __builtin_bit_cast(bf16x8, av);
}

// ============ weight staging split: load pass / transpose pass =============
// stg layout [k][n] stride st = N+1; dst [n][128] with consumer XOR swizzle.
// Split so multiple matrices' global loads share one barrier (MLP) and the
// caller controls barrier placement (4 barriers total instead of 8).
template<bool BF>
__device__ __forceinline__ void stg_load(const void* src, u16* stg, int N, int st)
{
    int t = threadIdx.x;
    int items1 = (128 * N) >> 2;
    for (int i = t; i < items1; i += 512) {
        int e = i << 2;                       // element index (consecutive)
        u16 a, b, c, d;
        if (BF) {
            u16x4 v = *(const u16x4*)((const u16*)src + e);
            a = v.x; b = v.y; c = v.z; d = v.w;
        } else {
            f32x4 v = *(const f32x4*)((const float*)src + e);
            a = f2b_raw(v.x); b = f2b_raw(v.y); c = f2b_raw(v.z); d = f2b_raw(v.w);
        }
        int k = (N == 128) ? (e >> 7) : (e >> 6);
        int vv = (N == 128) ? (e & 127) : (e & 63);
        stg[k * st + vv]     = a;
        stg[k * st + vv + 1] = b;
        stg[k * st + vv + 2] = c;
        stg[k * st + vv + 3] = d;
    }
}
template<bool BF>
__device__ __forceinline__ void stg_xpose(u16* dst, const u16* stg, int N, int st)
{
    int t = threadIdx.x;
    int items2 = (N * 128) >> 2;
    for (int j = t; j < items2; j += 512) {
        int n = j >> 5, k4 = (j & 31) << 2;
        u16x4 o;
        o.x = stg[(k4 + 0) * st + n];
        o.y = stg[(k4 + 1) * st + n];
        o.z = stg[(k4 + 2) * st + n];
        o.w = stg[(k4 + 3) * st + n];
        *(u16x4*)&dst[n * 128 + (k4 ^ ((n & 7) << 3))] = o;
    }
}

// ============ k_main: 256 blocks (qt, bwf) x 512 thr =======================
// XCD-spread decode: qt = bx>>6 (4 groups of 64), bwf = bx&63.
template<bool BF>
__device__ __forceinline__ void main_body(
    const void* query, const void* fragment, const void* qmask, const void* fmask,
    const void* projB, const void* saW, const void* gatew, const void* valw,
    const void* projW, const void* qattW, const void* qfW, const void* fattW,
    float* ws, void* out, char* smem)
{
    u16*   s_fp  = (u16*)(smem + L_FP);
    u16*   s_qp  = (u16*)(smem + L_QP);
    u16*   s_fa  = (u16*)(smem + L_FA);
    u16*   s_qat = (u16*)(smem + L_QAT);
    float* s_saw = (float*)(smem + L_SAW);
    float* s_att = (float*)(smem + L_ATT);
    float* s_red = (float*)(smem + L_RED);
    u16*   s_pm  = (u16*)(smem + L_PM);
    u16*   pwt   = (u16*)(smem + L_PWT);
    u16*   qatw  = (u16*)(smem + L_QATW);
    u16*   w3t   = (u16*)(smem + L_W3T);
    u16*   wft   = (u16*)(smem + L_WFT);
    float* s_e2  = (float*)(smem + L_E2);

    int bx = blockIdx.x;
    int qt = bx >> 6, bwf = bx & 63, b = bwf >> 4;
    int t = threadIdx.x, lane = t & 63, w = t >> 6;
    int m = lane & 15, quad = lane >> 4;
    int sk = (m & 7) << 3;
    bool do_fragatt = (qt == (bwf & 3));
    bool do_export  = ((bwf & 15) == 0);

    // ---- Hoisted Phase-A global loads: issue before staging so HBM/L2
    // latency hides under the whole Phase-W LDS work (no barrier between
    // issue and first use drains them early; compiler keeps them in flight).
    bf16x8 a_in[4];
    float  bvv[8];
    if (w < 4) {
        #pragma unroll
        for (int kt = 0; kt < 4; ++kt)
            a_in[kt] = loadA<BF>(fragment, bwf * 64 + w * 16 + m, kt, quad);
    } else if (w < 6) {
        int q0 = (w - 4) * 16;
        #pragma unroll
        for (int kt = 0; kt < 4; ++kt)
            a_in[kt] = loadA<BF>(query, b * 128 + qt * 32 + q0 + m, kt, quad);
    }
    if (w < 6) {
        #pragma unroll
        for (int nt = 0; nt < 8; ++nt) bvv[nt] = LD<BF>(projB, nt * 16 + m);
    }

    // ---- Phase W: stage weight transposes into LDS (2 barrier groups) ----
    {
        u16* sc = (u16*)smem;
        stg_load<BF>(projW, sc, 128, 129);              // 33.0 KB scratch
        __syncthreads();
        stg_xpose<BF>(pwt, sc, 128, 129);
        __syncthreads();
        stg_load<BF>(qattW, sc,         64, 65);        // 3 x 16.6 KB scratch
        stg_load<BF>(qfW,   sc + 8320,  64, 65);
        stg_load<BF>(fattW, sc + 16640, 64, 65);
        __syncthreads();
        stg_xpose<BF>(qatw, sc,         64, 65);
        stg_xpose<BF>(w3t,  sc + 8320,  64, 65);
        stg_xpose<BF>(wft,  sc + 16640, 64, 65);
        __syncthreads();
    }

    // ---- Phase A: projections ----
    if (w < 4) {
        // fragment rows [w*16, w*16+16)
        #pragma unroll
        for (int nt = 0; nt < 8; ++nt) {
            int n = nt * 16 + m;
            float bv = bvv[nt];
            f32x4 acc = (f32x4){bv, bv, bv, bv};
            #pragma unroll
            for (int kt = 0; kt < 4; ++kt) {
                bf16x8 bw = *(const bf16x8*)&pwt[n * 128 + ((kt * 32 + quad * 8) ^ sk)];
                acc = __builtin_amdgcn_mfma_f32_16x16x32_bf16(a_in[kt], bw, acc, 0, 0, 0);
            }
            #pragma unroll
            for (int rr = 0; rr < 4; ++rr) {
                int row = w * 16 + quad * 4 + rr;
                s_fp[row * 128 + (n ^ ((row & 7) << 3))] = f2b_raw(acc[rr]);
            }
        }
    } else if (w < 6) {
        // query rows qt*32 + (w-4)*16 + [0,16)
        int q0 = (w - 4) * 16;
        #pragma unroll
        for (int nt = 0; nt < 8; ++nt) {
            int n = nt * 16 + m;
            float bv = bvv[nt];
            f32x4 acc = (f32x4){bv, bv, bv, bv};
            #pragma unroll
            for (int kt = 0; kt < 4; ++kt) {
                bf16x8 bw = *(const bf16x8*)&pwt[n * 128 + ((kt * 32 + quad * 8) ^ sk)];
                acc = __builtin_amdgcn_mfma_f32_16x16x32_bf16(a_in[kt], bw, acc, 0, 0, 0);
            }
            #pragma unroll
            for (int rr = 0; rr < 4; ++rr) {
                int row = q0 + quad * 4 + rr;
                s_qp[row * 128 + (n ^ ((row & 7) << 3))] = f2b_raw(acc[rr]);
            }
        }
    }
    __syncthreads();

    // ---- Phase B: f_att (waves 0-3) and q_att (waves 4-5) ----
    if (w < 4) {
        bf16x8 afa[4];
        #pragma unroll
        for (int kt = 0; kt < 4; ++kt)
            afa[kt] = *(const bf16x8*)&s_fp[(w * 16 + m) * 128 + ((kt * 32 + quad * 8) ^ sk)];
        #pragma unroll
        for (int vt = 0; vt < 4; ++vt) {
            f32x4 a0 = (f32x4){0.f, 0.f, 0.f, 0.f};
            #pragma unroll
            for (int kt = 0; kt < 4; ++kt) {
                bf16x8 wk = *(const bf16x8*)&wft[(vt * 16 + m) * 128 + ((kt * 32 + quad * 8) ^ sk)];
                a0 = __builtin_amdgcn_mfma_f32_16x16x32_bf16(afa[kt], wk, a0, 0, 0, 0);
            }
            #pragma unroll
            for (int r = 0; r < 4; ++r)
                s_fa[(w * 16 + quad * 4 + r) * 72 + vt * 16 + m] = f2b_raw(a0[r]);
        }
    } else if (w < 6) {
        int q0 = (w - 4) * 16;
        bf16x8 aq[4];
        #pragma unroll
        for (int kt = 0; kt < 4; ++kt)
            aq[kt] = *(const bf16x8*)&s_qp[(q0 + m) * 128 + ((kt * 32 + quad * 8) ^ sk)];
        #pragma unroll
        for (int vt = 0; vt < 4; ++vt) {
            f32x4 a0 = (f32x4){0.f, 0.f, 0.f, 0.f};
            #pragma unroll
            for (int kt = 0; kt < 4; ++kt) {
                bf16x8 bk = *(const bf16x8*)&qatw[(vt * 16 + m) * 128 + ((kt * 32 + quad * 8) ^ sk)];
                a0 = __builtin_amdgcn_mfma_f32_16x16x32_bf16(aq[kt], bk, a0, 0, 0, 0);
            }
            #pragma unroll
            for (int r = 0; r < 4; ++r)
                s_qat[(q0 + quad * 4 + r) * 72 + vt * 16 + m] = f2b_raw(a0[r]);
        }
    }
    __syncthreads();

    // ---- Phase C: l-loop. wave = (qsub, lq) -> 16q x 16l x ALL 4 vt ----
    int qsub = w & 1, lq = w >> 1;          // lq in [0,4): 16-l quarter
    bf16x8 w3f[4][4];
    #pragma unroll
    for (int vt = 0; vt < 4; ++vt)
        #pragma unroll
        for (int kt = 0; kt < 4; ++kt)
            w3f[vt][kt] = *(const bf16x8*)&w3t[(vt * 16 + m) * 128 + ((kt * 32 + quad * 8) ^ sk)];
    f32x2 qp2[4][4];
    {
        #pragma unroll
        for (int kt = 0; kt < 4; ++kt) {
            bf16x8 aq2 = *(const bf16x8*)&s_qp[(qsub * 16 + m) * 128 + ((kt * 32 + quad * 8) ^ sk)];
            u32x4 uv = __builtin_bit_cast(u32x4, aq2);
            qp2[kt][0] = (f32x2){lo2f(uv.x), hi2f(uv.x)};
            qp2[kt][1] = (f32x2){lo2f(uv.y), hi2f(uv.y)};
            qp2[kt][2] = (f32x2){lo2f(uv.z), hi2f(uv.z)};
            qp2[kt][3] = (f32x2){lo2f(uv.w), hi2f(uv.w)};
        }
    }
    float mx[4][4];
    #pragma unroll
    for (int vt = 0; vt < 4; ++vt)
        #pragma unroll
        for (int r = 0; r < 4; ++r) mx[vt][r] = -1e30f;

    int lbase = lq * 16;
    #pragma unroll 2
    for (int li = 0; li < 16; ++li) {
        int l = lbase + li;
        int sw = (l & 7) << 3;
        bf16x8 af[4];
        #pragma unroll
        for (int kt = 0; kt < 4; ++kt) {
            u32x4 fv = *(const u32x4*)&s_fp[l * 128 + ((kt * 32 + quad * 8) ^ sw)];
            f32x2 p0 = qp2[kt][0] * (f32x2){lo2f(fv.x), hi2f(fv.x)};
            f32x2 p1 = qp2[kt][1] * (f32x2){lo2f(fv.y), hi2f(fv.y)};
            f32x2 p2 = qp2[kt][2] * (f32x2){lo2f(fv.z), hi2f(fv.z)};
            f32x2 p3 = qp2[kt][3] * (f32x2){lo2f(fv.w), hi2f(fv.w)};
            u32x4 av;
            av.x = pk2(p0.y, p0.x);
            av.y = pk2(p1.y, p1.x);
            av.z = pk2(p2.y, p2.x);
            av.w = pk2(p3.y, p3.x);
            af[kt] = __builtin_bit_cast(bf16x8, av);
        }
        #pragma unroll
        for (int vt = 0; vt < 4; ++vt) {
            float fa = us2f(s_fa[l * 72 + vt * 16 + m]);
            f32x4 acc = (f32x4){fa, fa, fa, fa};
            #pragma unroll
            for (int kt = 0; kt < 4; ++kt)
                acc = __builtin_amdgcn_mfma_f32_16x16x32_bf16(af[kt], w3f[vt][kt], acc, 0, 0, 0);
            #pragma unroll
            for (int r = 0; r < 4; ++r) mx[vt][r] = fmaxf(mx[vt][r], acc[r]);
        }
    }
    // partial maxes to dedicated s_pm (bank-swizzled)
    #pragma unroll
    for (int vt = 0; vt < 4; ++vt)
        #pragma unroll
        for (int r = 0; r < 4; ++r) {
            int q = qsub * 16 + quad * 4 + r;
            s_pm[(lq * 32 + q) * 64 + ((vt * 16 + m) ^ (((q >> 2) & 3) << 4))] = f2b_raw(mx[vt][r]);
        }
    __syncthreads();

    // ---- Phase D: gate / e2 epilogue (q = t>>4 in [0,32), vg = t&15) ----
    {
        int q = t >> 4, vg = t & 15;
        int gq = qt * 32 + q;
        int swq = ((q >> 2) & 3) << 4;
        float gp = 0.f, ep = 0.f;
        #pragma unroll
        for (int jj = 0; jj < 4; ++jj) {
            int v = vg * 4 + jj;
            int c = v ^ swq;
            float m01 = fmaxf(us2f(s_pm[q * 64 + c]),        us2f(s_pm[(32 + q) * 64 + c]));
            float m23 = fmaxf(us2f(s_pm[(64 + q) * 64 + c]), us2f(s_pm[(96 + q) * 64 + c]));
            float qf = fmaxf(m01, m23) + us2f(s_qat[q * 72 + v]);
            gp += qf * LD<BF>(gatew, v);
            ep += qf * LD<BF>(valw, v);
        }
        #pragma unroll
        for (int off = 1; off <= 8; off <<= 1) {
            gp += __shfl_xor(gp, off, 64);
            ep += __shfl_xor(ep, off, 64);
        }
        if (vg == 0) {
            float qm = LD<BF>(qmask, b * 128 + gq);
            float g = (1.0f / (1.0f + expf(-gp))) * qm;
            ST<BF>(out, OUT_QFGATE + bwf * LQ_ + gq, g);
            s_e2[q] = expf(ep) * qm;
        }
    }
    __syncthreads();

    // ---- Phase E: query_code partials (linear in e2, no normalization) ----
    // N_qt[d] = sum_{q in this block's 32} qp[q][d] * e2[q];  S_qt = sum e2.
    {
        int d = t & 127, grp = t >> 7;   // 4 groups x 8 q each
        float pa = 0.f;
        #pragma unroll
        for (int qi = 0; qi < 8; ++qi) {
            int q = grp * 8 + qi;
            pa += us2f(s_qp[q * 128 + (d ^ ((q & 7) << 3))]) * s_e2[q];
        }
        s_red[grp * 128 + d] = pa;
    }
    __syncthreads();
    if (t < 128)
        ws[WS_QCN + (qt * 64 + bwf) * 128 + t] =
            s_red[t] + s_red[128 + t] + s_red[256 + t] + s_red[384 + t];
    if (t == 0) {
        float S = 0.f;
        #pragma unroll
        for (int q = 0; q < 32; ++q) S += s_e2[q];
        ws[WS_QCS + qt * 64 + bwf] = S;
    }
    __syncthreads();   // s_red reused by fragatt below

    // ---- qp export (bwf%16==0 blocks; each exports its own 32 q rows) ----
    if (do_export) {
        #pragma unroll
        for (int it = 0; it < 8; ++it) {
            int i = t + 512 * it;              // 4096 = 32*128
            int row = i >> 7, col = i & 127;
            u16 raw = s_qp[row * 128 + (col ^ ((row & 7) << 3))];
            int gr = b * 128 + qt * 32 + row;
            ST<BF>(out, OUT_QUERY + gr * 128 + col, us2f(raw));
        }
    }

    // ---- fragment self-attention + frag_code (XCD-spread assignment) ----
    if (do_fragatt) {
        if (t < 128) s_saw[t] = LD<BF>(saW, ((bwf >> 3) & 1) * 128 + t);
        __syncthreads();
        {
            int l = t >> 3, j8 = t & 7;
            int swz = (l & 7) << 3;
            float p = 0.f;
            #pragma unroll
            for (int seg = 0; seg < 2; ++seg) {
                int koff = j8 * 16 + seg * 8;
                u32x4 fv = *(const u32x4*)&s_fp[l * 128 + (koff ^ swz)];
                const float* swp = &s_saw[koff];
                p += lo2f(fv.x) * swp[0] + hi2f(fv.x) * swp[1]
                   + lo2f(fv.y) * swp[2] + hi2f(fv.y) * swp[3]
                   + lo2f(fv.z) * swp[4] + hi2f(fv.z) * swp[5]
                   + lo2f(fv.w) * swp[6] + hi2f(fv.w) * swp[7];
            }
            p += __shfl_xor(p, 1, 64);
            p += __shfl_xor(p, 2, 64);
            p += __shfl_xor(p, 4, 64);
            if (j8 == 0) s_att[l] = expf(p) * LD<BF>(fmask, bwf * LF_ + l);
        }
        __syncthreads();
        if (t < 64) {
            float e = s_att[t], s = e;
            #pragma unroll
            for (int off = 1; off <= 32; off <<= 1) s += __shfl_xor(s, off, 64);
            float nrm = e / (s + 1e-7f);
            s_att[t] = nrm;
            ST<BF>(out, OUT_SELFATT + bwf * LF_ + t, nrm);
        }
        __syncthreads();
        {
            int d = t & 127, grp = t >> 7;
            float fc = 0.f;
            #pragma unroll
            for (int li2 = 0; li2 < 16; ++li2) {
                int l2 = grp * 16 + li2;
                fc += us2f(s_fp[l2 * 128 + (d ^ ((l2 & 7) << 3))]) * s_att[l2];
            }
            s_red[grp * 128 + d] = fc;
        }
        __syncthreads();
        if (t < 128)
            ST<BF>(out, OUT_FRAGCODE + bwf * D_ + t,
                   s_red[t] + s_red[128 + t] + s_red[256 + t] + s_red[384 + t]);
    }
}

__global__ __launch_bounds__(512, 2) void k_main3(
    const void* query, const void* fragment, const void* qmask, const void* fmask,
    const void* projB, const void* saW, const void* gatew, const void* valw,
    const void* projW, const void* qattW, const void* qfW, const void* fattW,
    float* ws, void* out)
{
    __shared__ __align__(16) char smem[L_TOT];
    if (is_bf(qmask))
        main_body<true >(query, fragment, qmask, fmask, projB, saW, gatew, valw,
                         projW, qattW, qfW, fattW, ws, out, smem);
    else
        main_body<false>(query, fragment, qmask, fmask, projB, saW, gatew, valw,
                         projW, qattW, qfW, fattW, ws, out, smem);
}

// ============ k_combine: 64 blocks x 128 thr — sum 4 qt partials ==========
template<bool BF>
__device__ __forceinline__ void combine_body(const float* ws, void* out)
{
    int bwf = blockIdx.x, t = threadIdx.x;
    float den = ws[WS_QCS + bwf] + ws[WS_QCS + 64 + bwf]
              + ws[WS_QCS + 128 + bwf] + ws[WS_QCS + 192 + bwf] + 1e-7f;
    float num = ws[WS_QCN + (bwf) * 128 + t]
              + ws[WS_QCN + (64 + bwf) * 128 + t]
              + ws[WS_QCN + (128 + bwf) * 128 + t]
              + ws[WS_QCN + (192 + bwf) * 128 + t];
    ST<BF>(out, OUT_QUERYCODE + bwf * D_ + t, num / den);
}
__global__ __launch_bounds__(128) void k_combine(const void* qmask, const float* ws, void* out)
{
    if (is_bf(qmask)) combine_body<true >(ws, out);
    else              combine_body<false>(ws, out);
}

extern "C" void kernel_launch(void* const* d_in, const int* in_sizes, int n_in,
                              void* d_out, int out_size, void* d_ws, size_t ws_size,
                              hipStream_t stream)
{
    const void* query    = d_in[0];
    const void* fragment = d_in[1];
    const void* qmask    = d_in[2];
    const void* fmask    = d_in[3];
    const void* projW    = d_in[4];
    const void* projB    = d_in[5];
    const void* saW      = d_in[6];
    const void* qattW    = d_in[7];
    const void* fattW    = d_in[8];
    const void* qfW      = d_in[9];
    const void* gatew    = d_in[10];
    const void* valw     = d_in[11];
    float* ws = (float*)d_ws;

    hipLaunchKernelGGL(k_main3, dim3(256), dim3(512), 0, stream,
                       query, fragment, qmask, fmask, projB, saW, gatew, valw,
                       projW, qattW, qfW, fattW, ws, d_out);
    hipLaunchKernelGGL(k_combine, dim3(B_ * NWF_), dim3(128), 0, stream,
                       qmask, ws, d_out);
}